// Round 13
// baseline (107.821 us; speedup 1.0000x reference)
//
#include <hip/hip_runtime.h>
#include <math.h>

// NoisyTopkRouter: B=4,S=4096,D=2048,E=64,TOP_K=8
//   convert_w   : W -> packed bf16 hi/lo (Wpk); zeroes flag counter  [frozen]
//   gemm_k1     : split-bf16 MFMA GEMM -> scores [M][128] f32
//                 r13 change: __launch_bounds__(512,2) (was (512,4)) — the
//                 (512,4) bound capped VGPRs at 64 < the ~100 live (bE+bO
//                 B-dbuf = 64 VGPR alone), forcing scratch spills inside the
//                 MFMA loop (VGPR_Count=56, MfmaUtil 9.5%, all pipes idle).
//   epi_fast    : one wave/token fast path; near-ties -> flag list   [frozen]
//   refine_dots : one WAVE per (flagged token, expert) fp64 dots     [frozen]
//   refine_final: one wave per flagged token fp64 softmax/top-8      [frozen]

#define KDIM 2048
#define NEXP 64
#define BM 32
#define KB 64
#define NKB (KDIM / KB)
#define TAU 1.5e-4f

typedef __attribute__((ext_vector_type(8))) short short8v;
typedef __attribute__((ext_vector_type(4))) float f32x4;

__device__ __forceinline__ void bsplit(float v, ushort& h, ushort& l) {
  unsigned u = __float_as_uint(v);
  unsigned hu = (u + 0x8000u) & 0xFFFF0000u;
  h = (ushort)(hu >> 16);
  float r = v - __uint_as_float(hu);
  l = (ushort)((__float_as_uint(r) + 0x8000u) >> 16);
}

__global__ __launch_bounds__(256)
void convert_w(const float* __restrict__ Wr, const float* __restrict__ Wn,
               ushort* __restrict__ Wpk, int* __restrict__ flagcnt) {
  if (blockIdx.x == 0 && threadIdx.x == 0) *flagcnt = 0;
  const int g = blockIdx.x * 256 + threadIdx.x;
  const int row = g >> 9;
  const int k0  = (g & 511) << 2;
  const int c   = k0 >> 5;
  const int kk  = k0 & 31;
  const float* src = (row < NEXP) ? (Wr + (size_t)row * KDIM + k0)
                                  : (Wn + (size_t)(row - NEXP) * KDIM + k0);
  const float4 v = *(const float4*)src;
  ushort4 h, l;
  bsplit(v.x, h.x, l.x); bsplit(v.y, h.y, l.y);
  bsplit(v.z, h.z, l.z); bsplit(v.w, h.w, l.w);
  *(ushort4*)(Wpk + ((size_t)(c * 2 + 0) * 128 + row) * 32 + kk) = h;
  *(ushort4*)(Wpk + ((size_t)(c * 2 + 1) * 128 + row) * 32 + kk) = l;
}

struct BSet { short8v h00, h01, l00, l01, h10, h11, l10, l11; };

__device__ __forceinline__ BSet loadB(const ushort* base, int blk) {
  BSet b;
  const ushort* p0 = base + (size_t)blk * 16384;
  b.h00 = *(const short8v*)(p0);
  b.h01 = *(const short8v*)(p0 + 512);
  b.l00 = *(const short8v*)(p0 + 4096);
  b.l01 = *(const short8v*)(p0 + 4096 + 512);
  b.h10 = *(const short8v*)(p0 + 8192);
  b.h11 = *(const short8v*)(p0 + 8192 + 512);
  b.l10 = *(const short8v*)(p0 + 12288);
  b.l11 = *(const short8v*)(p0 + 12288 + 512);
  return b;
}

#define ALD(arr, P, ROW, KH) \
  (*(const short8v*)((const char*)&arr[P][0] + ((ROW) << 7) + (((((KH)*4 + lg)) ^ ((ROW) & 7)) << 4)))

__global__ __launch_bounds__(512, 2)
void gemm_k1(const float* __restrict__ x, const ushort* __restrict__ Wpk,
             float* __restrict__ scores)
{
  __shared__ ushort AhBuf[2][32 * 64];
  __shared__ ushort AlBuf[2][32 * 64];

  const int tid  = threadIdx.x;
  const int row0 = blockIdx.x * BM;

  const int srow  = tid >> 4;
  const int sk4   = (tid & 15) << 2;
  const int sunit = sk4 >> 3;
  const int sbyte = (srow << 7) + ((sunit ^ (srow & 7)) << 4) + ((sk4 & 4) << 1);
  const float* xrow = x + (size_t)(row0 + srow) * KDIM + sk4;

  const int wid  = tid >> 6;
  const int lane = tid & 63;
  const int lr   = lane & 15;
  const int lg   = lane >> 4;
  const int mg   = wid >> 2;
  const int cg   = wid & 3;
  const int arow = mg * 16 + lr;

  const ushort* Wb = Wpk + (size_t)(cg * 32 + lr) * 32 + lg * 8;

  f32x4 acc0 = {0.f, 0.f, 0.f, 0.f}, acc1 = {0.f, 0.f, 0.f, 0.f};

  {
    const float4 x0 = *(const float4*)(xrow);
    ushort4 h, l;
    bsplit(x0.x, h.x, l.x); bsplit(x0.y, h.y, l.y);
    bsplit(x0.z, h.z, l.z); bsplit(x0.w, h.w, l.w);
    *(ushort4*)((char*)&AhBuf[0][0] + sbyte) = h;
    *(ushort4*)((char*)&AlBuf[0][0] + sbyte) = l;
  }
  float4 xq1 = *(const float4*)(xrow + 1 * KB);
  float4 xq2 = *(const float4*)(xrow + 2 * KB);
  BSet bE = loadB(Wb, 0);
  BSet bO = loadB(Wb, 1);
  __syncthreads();

  for (int s = 0; s < NKB; s += 2) {
    {
      ushort4 h, l;
      bsplit(xq1.x, h.x, l.x); bsplit(xq1.y, h.y, l.y);
      bsplit(xq1.z, h.z, l.z); bsplit(xq1.w, h.w, l.w);
      *(ushort4*)((char*)&AhBuf[1][0] + sbyte) = h;
      *(ushort4*)((char*)&AlBuf[1][0] + sbyte) = l;
    }
    { const int nb = (s + 3 < NKB) ? s + 3 : NKB - 1;
      xq1 = *(const float4*)(xrow + nb * KB); }
    {
      const short8v ah0 = ALD(AhBuf, 0, arow, 0);
      const short8v al0 = ALD(AlBuf, 0, arow, 0);
      acc0 = __builtin_amdgcn_mfma_f32_16x16x32_bf16(ah0, bE.h00, acc0, 0, 0, 0);
      acc1 = __builtin_amdgcn_mfma_f32_16x16x32_bf16(ah0, bE.h01, acc1, 0, 0, 0);
      acc0 = __builtin_amdgcn_mfma_f32_16x16x32_bf16(ah0, bE.l00, acc0, 0, 0, 0);
      acc1 = __builtin_amdgcn_mfma_f32_16x16x32_bf16(ah0, bE.l01, acc1, 0, 0, 0);
      acc0 = __builtin_amdgcn_mfma_f32_16x16x32_bf16(al0, bE.h00, acc0, 0, 0, 0);
      acc1 = __builtin_amdgcn_mfma_f32_16x16x32_bf16(al0, bE.h01, acc1, 0, 0, 0);
      const short8v ah1 = ALD(AhBuf, 0, arow, 1);
      const short8v al1 = ALD(AlBuf, 0, arow, 1);
      acc0 = __builtin_amdgcn_mfma_f32_16x16x32_bf16(ah1, bE.h10, acc0, 0, 0, 0);
      acc1 = __builtin_amdgcn_mfma_f32_16x16x32_bf16(ah1, bE.h11, acc1, 0, 0, 0);
      acc0 = __builtin_amdgcn_mfma_f32_16x16x32_bf16(ah1, bE.l10, acc0, 0, 0, 0);
      acc1 = __builtin_amdgcn_mfma_f32_16x16x32_bf16(ah1, bE.l11, acc1, 0, 0, 0);
      acc0 = __builtin_amdgcn_mfma_f32_16x16x32_bf16(al1, bE.h10, acc0, 0, 0, 0);
      acc1 = __builtin_amdgcn_mfma_f32_16x16x32_bf16(al1, bE.h11, acc1, 0, 0, 0);
    }
    { const int nb = (s + 2 < NKB) ? s + 2 : NKB - 1; bE = loadB(Wb, nb); }
    __syncthreads();

    {
      ushort4 h, l;
      bsplit(xq2.x, h.x, l.x); bsplit(xq2.y, h.y, l.y);
      bsplit(xq2.z, h.z, l.z); bsplit(xq2.w, h.w, l.w);
      *(ushort4*)((char*)&AhBuf[0][0] + sbyte) = h;
      *(ushort4*)((char*)&AlBuf[0][0] + sbyte) = l;
    }
    { const int nb = (s + 4 < NKB) ? s + 4 : NKB - 1;
      xq2 = *(const float4*)(xrow + nb * KB); }
    {
      const short8v ah0 = ALD(AhBuf, 1, arow, 0);
      const short8v al0 = ALD(AlBuf, 1, arow, 0);
      acc0 = __builtin_amdgcn_mfma_f32_16x16x32_bf16(ah0, bO.h00, acc0, 0, 0, 0);
      acc1 = __builtin_amdgcn_mfma_f32_16x16x32_bf16(ah0, bO.h01, acc1, 0, 0, 0);
      acc0 = __builtin_amdgcn_mfma_f32_16x16x32_bf16(ah0, bO.l00, acc0, 0, 0, 0);
      acc1 = __builtin_amdgcn_mfma_f32_16x16x32_bf16(ah0, bO.l01, acc1, 0, 0, 0);
      acc0 = __builtin_amdgcn_mfma_f32_16x16x32_bf16(al0, bO.h00, acc0, 0, 0, 0);
      acc1 = __builtin_amdgcn_mfma_f32_16x16x32_bf16(al0, bO.h01, acc1, 0, 0, 0);
      const short8v ah1 = ALD(AhBuf, 1, arow, 1);
      const short8v al1 = ALD(AlBuf, 1, arow, 1);
      acc0 = __builtin_amdgcn_mfma_f32_16x16x32_bf16(ah1, bO.h10, acc0, 0, 0, 0);
      acc1 = __builtin_amdgcn_mfma_f32_16x16x32_bf16(ah1, bO.h11, acc1, 0, 0, 0);
      acc0 = __builtin_amdgcn_mfma_f32_16x16x32_bf16(ah1, bO.l10, acc0, 0, 0, 0);
      acc1 = __builtin_amdgcn_mfma_f32_16x16x32_bf16(ah1, bO.l11, acc1, 0, 0, 0);
      acc0 = __builtin_amdgcn_mfma_f32_16x16x32_bf16(al1, bO.h10, acc0, 0, 0, 0);
      acc1 = __builtin_amdgcn_mfma_f32_16x16x32_bf16(al1, bO.h11, acc1, 0, 0, 0);
    }
    { const int nb = (s + 3 < NKB) ? s + 3 : NKB - 1; bO = loadB(Wb, nb); }
    __syncthreads();
  }

#pragma unroll
  for (int rr = 0; rr < 4; ++rr) {
    const int trow = row0 + mg * 16 + lg * 4 + rr;
    scores[(size_t)trow * 128 + cg * 32 + lr]      = acc0[rr];
    scores[(size_t)trow * 128 + cg * 32 + 16 + lr] = acc1[rr];
  }
}

// one wave per token: fast path only; near-ties appended to flag list
__global__ __launch_bounds__(512, 4)
void epi_fast(const float* __restrict__ scores,
              const float* __restrict__ br, const float* __restrict__ bn,
              const float* __restrict__ noise,
              float* __restrict__ out_w, float* __restrict__ out_i,
              float* __restrict__ out_s,
              int* __restrict__ flagcnt, int* __restrict__ flaglist)
{
  const int wid  = threadIdx.x >> 6;
  const int lane = threadIdx.x & 63;
  const int t    = blockIdx.x * 8 + wid;

  const float sr = scores[(size_t)t * 128 + lane];
  const float sn = scores[(size_t)t * 128 + 64 + lane];
  const float z  = sn + bn[lane];
  const float sp = fmaxf(z, 0.f) + log1pf(expf(-fabsf(z)));
  const float v  = sr + br[lane] + noise[(size_t)t * NEXP + lane] * sp;

  float m = v;
#pragma unroll
  for (int d = 32; d; d >>= 1) m = fmaxf(m, __shfl_xor(m, d));
  const float p = expf(v - m);
  float sum = p;
#pragma unroll
  for (int d = 32; d; d >>= 1) sum += __shfl_xor(sum, d);
  out_s[(size_t)t * NEXP + lane] = p / sum;

  float cur = v;
  float vals9[9]; int idx9[9];
#pragma unroll
  for (int it = 0; it < 9; ++it) {
    float mx = cur;
#pragma unroll
    for (int d = 32; d; d >>= 1) mx = fmaxf(mx, __shfl_xor(mx, d));
    const unsigned long long b = __ballot(cur == mx);
    const int li = __ffsll(b) - 1;                 // ties -> lowest index
    vals9[it] = mx; idx9[it] = li;
    if (lane == li) cur = -INFINITY;
  }
  bool flagged = false;
#pragma unroll
  for (int q = 0; q < 8; ++q) flagged |= (vals9[q] - vals9[q + 1] < TAU);

  if (flagged) {
    if (lane == 0) {
      const int s = atomicAdd(flagcnt, 1);
      flaglist[s] = t;
    }
    return;                                        // refine_* writes outputs
  }

  float pt[8]; float ws = 0.f;
#pragma unroll
  for (int q = 0; q < 8; ++q) { pt[q] = expf(vals9[q] - m); ws += pt[q]; }
  if (lane < 8) {
    out_w[(size_t)t * 8 + lane] = pt[lane] / ws;
    out_i[(size_t)t * 8 + lane] = (float)idx9[lane];
  }
}

// one WAVE per (flagged token, expert): nf*64 wave-jobs, grid-strided
__global__ __launch_bounds__(512)
void refine_dots(const float* __restrict__ x,
                 const float* __restrict__ Wr, const float* __restrict__ Wn,
                 const float* __restrict__ br, const float* __restrict__ bn,
                 const float* __restrict__ noise,
                 const int* __restrict__ flagcnt, const int* __restrict__ flaglist,
                 double* __restrict__ nv64)
{
  const int nf    = *flagcnt;
  const int lane  = threadIdx.x & 63;
  const int wslot = (blockIdx.x * 512 + threadIdx.x) >> 6;
  const int nwav  = (gridDim.x * 512) >> 6;
  const int total = nf * 64;

  for (int w = wslot; w < total; w += nwav) {
    const int i = w >> 6, e = w & 63;
    const int t = flaglist[i];
    const float* xr  = x  + (size_t)t * KDIM + lane * 4;
    const float* wrr = Wr + (size_t)e * KDIM + lane * 4;
    const float* wnr = Wn + (size_t)e * KDIM + lane * 4;
    double a0 = 0, a1 = 0, c0 = 0, c1 = 0;
#pragma unroll
    for (int q = 0; q < 8; ++q) {
      const float4 xv = *(const float4*)(xr  + q * 256);
      const float4 wv = *(const float4*)(wrr + q * 256);
      const float4 nv = *(const float4*)(wnr + q * 256);
      a0 = fma((double)xv.x, (double)wv.x, a0);
      a1 = fma((double)xv.y, (double)wv.y, a1);
      a0 = fma((double)xv.z, (double)wv.z, a0);
      a1 = fma((double)xv.w, (double)wv.w, a1);
      c0 = fma((double)xv.x, (double)nv.x, c0);
      c1 = fma((double)xv.y, (double)nv.y, c1);
      c0 = fma((double)xv.z, (double)nv.z, c0);
      c1 = fma((double)xv.w, (double)nv.w, c1);
    }
    double ar = a0 + a1, an = c0 + c1;
#pragma unroll
    for (int d = 32; d; d >>= 1) {
      ar += __shfl_xor(ar, d);
      an += __shfl_xor(an, d);
    }
    if (lane == 0) {
      const double rte = ar + (double)br[e];
      const double zz  = an + (double)bn[e];
      const double spd = fmax(zz, 0.0) + log1p(exp(-fabs(zz)));
      nv64[(size_t)i * 64 + e] = rte + (double)noise[(size_t)t * NEXP + e] * spd;
    }
  }
}

// one wave per flagged token: proven fp64 softmax/top-8 tail
__global__ __launch_bounds__(512)
void refine_final(const double* __restrict__ nv64,
                  const int* __restrict__ flagcnt, const int* __restrict__ flaglist,
                  float* __restrict__ out_w, float* __restrict__ out_i,
                  float* __restrict__ out_s)
{
  const int nf    = *flagcnt;
  const int lane  = threadIdx.x & 63;
  const int wslot = (blockIdx.x * 512 + threadIdx.x) >> 6;
  const int nwav  = (gridDim.x * 512) >> 6;

  for (int i = wslot; i < nf; i += nwav) {
    const int t = flaglist[i];
    const double v64 = nv64[(size_t)i * 64 + lane];
    double md = v64;
#pragma unroll
    for (int d = 32; d; d >>= 1) md = fmax(md, __shfl_xor(md, d));
    const double pe = exp(v64 - md);
    double sd = pe;
#pragma unroll
    for (int d = 32; d; d >>= 1) sd += __shfl_xor(sd, d);
    out_s[(size_t)t * NEXP + lane] = (float)(pe / sd);

    double curd = v64;
    double pv8[8]; int pi8[8]; double wsd = 0.0;
#pragma unroll
    for (int it = 0; it < 8; ++it) {
      double mx = curd;
#pragma unroll
      for (int d = 32; d; d >>= 1) mx = fmax(mx, __shfl_xor(mx, d));
      const unsigned long long b = __ballot(curd == mx);
      const int li = __ffsll(b) - 1;
      pv8[it] = __shfl(pe, li); pi8[it] = li; wsd += pv8[it];
      if (lane == li) curd = -1e300;
    }
    if (lane < 8) {
      out_w[(size_t)t * 8 + lane] = (float)(pv8[lane] / wsd);
      out_i[(size_t)t * 8 + lane] = (float)pi8[lane];
    }
  }
}

extern "C" void kernel_launch(void* const* d_in, const int* in_sizes, int n_in,
                              void* d_out, int out_size, void* d_ws, size_t ws_size,
                              hipStream_t stream) {
  const float* x     = (const float*)d_in[0];
  const float* Wr    = (const float*)d_in[1];
  const float* br    = (const float*)d_in[2];
  const float* Wn    = (const float*)d_in[3];
  const float* bn    = (const float*)d_in[4];
  const float* noise = (const float*)d_in[5];

  const int M = in_sizes[0] / KDIM;                  // 16384 tokens
  float*  scores   = (float*)d_ws;                   // [M][128] f32 = 8 MB
  double* nv64     = (double*)d_ws;                  // aliases scores (dead after
                                                     // epi_fast): [i][64] f64
  ushort* Wpk      = (ushort*)(scores + (size_t)M * 128);  // 1 MB packed W
  int*    flagcnt  = (int*)(Wpk + (size_t)64 * 2 * 128 * 32);
  int*    flaglist = flagcnt + 1;                    // up to M ints

  float* out   = (float*)d_out;
  float* out_w = out;                                // [M,8]
  float* out_i = out + (size_t)M * 8;                // [M,8] indices as floats
  float* out_s = out + (size_t)M * 16;               // [M,64]

  convert_w<<<dim3(256), dim3(256), 0, stream>>>(Wr, Wn, Wpk, flagcnt);
  gemm_k1<<<dim3(M / BM), dim3(512), 0, stream>>>(x, Wpk, scores);
  epi_fast<<<dim3(M / 8), dim3(512), 0, stream>>>(scores, br, bn, noise,
                                                  out_w, out_i, out_s,
                                                  flagcnt, flaglist);
  refine_dots<<<dim3(1024), dim3(512), 0, stream>>>(x, Wr, Wn, br, bn, noise,
                                                    flagcnt, flaglist, nv64);
  refine_final<<<dim3(256), dim3(512), 0, stream>>>(nv64, flagcnt, flaglist,
                                                    out_w, out_i, out_s);
}

// Round 14
// 91.691 us; speedup vs baseline: 1.1759x; 1.1759x over previous
//
#include <hip/hip_runtime.h>
#include <math.h>

// NoisyTopkRouter: B=4,S=4096,D=2048,E=64,TOP_K=8
//   convert_w   : W -> per-K-block packed bf16 hi/lo, LDS-image layout with
//                 baked XOR swizzle (unit' = unit ^ ((row>>1)&3))
//   gemm_k1     : 64x128 tile, B staged via global_load_lds (async DMA, the
//                 compiler cannot sink it - r13 showed reg-prefetch gets
//                 rematerialized at use, exposing L2 latency), A reg->bsplit->
//                 swizzled ds_write, double-buffered, 1 barrier/K-block.
//   epi_fast    : one wave/token fast path; near-ties -> flag list   [frozen]
//   refine_dots : one WAVE per (flagged token, expert) fp64 dots     [frozen]
//   refine_final: one wave per flagged token fp64 softmax/top-8      [frozen]

#define KDIM 2048
#define NEXP 64
#define BM 64
#define KB 64
#define NKB (KDIM / KB)       // 32
#define TAU 1.5e-4f

typedef __attribute__((ext_vector_type(8))) short short8v;
typedef __attribute__((ext_vector_type(4))) float f32x4;

__device__ __forceinline__ void bsplit(float v, ushort& h, ushort& l) {
  unsigned u = __float_as_uint(v);
  unsigned hu = (u + 0x8000u) & 0xFFFF0000u;
  h = (ushort)(hu >> 16);
  float r = v - __uint_as_float(hu);
  l = (ushort)((__float_as_uint(r) + 0x8000u) >> 16);
}

// Wpk[blk 0..31][c2 0..1][part 0..1][row 0..127][unit' 0..3][8 bf16]
// unit' = unit ^ ((row>>1)&3)  -> conflict-free ds_read_b128 after linear DMA
__global__ __launch_bounds__(256)
void convert_w(const float* __restrict__ Wr, const float* __restrict__ Wn,
               ushort* __restrict__ Wpk, int* __restrict__ flagcnt) {
  if (blockIdx.x == 0 && threadIdx.x == 0) *flagcnt = 0;
  const int g = blockIdx.x * 256 + threadIdx.x;   // 32768 threads
  const int row = g >> 8;                         // 0..127
  const int ku  = g & 255;                        // k-unit (8 bf16 each)
  const int k   = ku * 8;
  const int blk  = ku >> 3;
  const int c2   = (ku >> 2) & 1;
  const int unit = ku & 3;
  const int up   = unit ^ ((row >> 1) & 3);
  const float* srcrow = (row < NEXP) ? (Wr + (size_t)row * KDIM)
                                     : (Wn + (size_t)(row - NEXP) * KDIM);
  const float4 v0 = *(const float4*)(srcrow + k);
  const float4 v1 = *(const float4*)(srcrow + k + 4);
  short8v hv, lv; ushort h, l;
  bsplit(v0.x, h, l); hv[0] = h; lv[0] = l;
  bsplit(v0.y, h, l); hv[1] = h; lv[1] = l;
  bsplit(v0.z, h, l); hv[2] = h; lv[2] = l;
  bsplit(v0.w, h, l); hv[3] = h; lv[3] = l;
  bsplit(v1.x, h, l); hv[4] = h; lv[4] = l;
  bsplit(v1.y, h, l); hv[5] = h; lv[5] = l;
  bsplit(v1.z, h, l); hv[6] = h; lv[6] = l;
  bsplit(v1.w, h, l); hv[7] = h; lv[7] = l;
  const size_t base = (size_t)blk * 16384 + (size_t)row * 32 + (size_t)up * 8;
  *(short8v*)(Wpk + base + (size_t)(c2 * 2 + 0) * 4096) = hv;
  *(short8v*)(Wpk + base + (size_t)(c2 * 2 + 1) * 4096) = lv;
}

__global__ __launch_bounds__(512, 1)
void gemm_k1(const float* __restrict__ x, const ushort* __restrict__ Wpk,
             float* __restrict__ scores)
{
  __shared__ ushort Bb[2][16384];   // 2 x 32KB  [c2][part][row][unit'][8]
  __shared__ ushort Ab[2][8192];    // 2 x 16KB  [part][row 0..63][unit' 0..7][8]

  const int tid  = threadIdx.x;
  const int row0 = blockIdx.x * BM;

  // A staging map: thread -> (row, k-unit)
  const int srow = tid >> 3;              // 0..63
  const int su   = tid & 7;               // unit 0..7 (k = su*8)
  const int sup  = su ^ (srow & 7);       // swizzled unit
  const float* xrow = x + (size_t)(row0 + srow) * KDIM + su * 8;
  ushort* aw0 = &Ab[0][(size_t)srow * 64 + sup * 8];          // part0
  ushort* aw1 = &Ab[0][(size_t)(64 + srow) * 64 + sup * 8];   // part1
  const int abufstride = 8192;

  // wave map: mg row-group (16 rows), cg col-half (64 cols)
  const int wid  = tid >> 6;
  const int lane = tid & 63;
  const int lr   = lane & 15;
  const int lg   = lane >> 4;
  const int mg   = wid >> 1;
  const int cg   = wid & 1;
  const int arow = mg * 16 + lr;

  // B DMA: wave wid copies bytes [wid*4KB, wid*4KB+4KB) of the 32KB tile
  const ushort* gB = Wpk + (size_t)(wid * 4) * 512 + lane * 8;

  f32x4 acc0 = {0,0,0,0}, acc1 = {0,0,0,0}, acc2 = {0,0,0,0}, acc3 = {0,0,0,0};

#define AIDX(part, row, u) ((size_t)((part) * 64 + (row)) * 64 + (size_t)((u) ^ ((row) & 7)) * 8)
#define BIDX(c2, part, rowb, u) ((size_t)(((c2) * 2 + (part)) * 128 + (rowb)) * 32 + (size_t)((u) ^ (((rowb) >> 1) & 3)) * 8)

  // prologue: stage block 0
  {
    const float4 xa = *(const float4*)(xrow);
    const float4 xb = *(const float4*)(xrow + 4);
#pragma unroll
    for (int j = 0; j < 4; ++j) {
      const ushort* gsrc = gB + (size_t)j * 512;   // + blk 0
      ushort* ldst = &Bb[0][(wid * 4 + j) * 512];
      __builtin_amdgcn_global_load_lds(
          (const __attribute__((address_space(1))) void*)gsrc,
          (__attribute__((address_space(3))) void*)ldst, 16, 0, 0);
    }
    short8v hv, lv; ushort h, l;
    bsplit(xa.x, h, l); hv[0] = h; lv[0] = l;
    bsplit(xa.y, h, l); hv[1] = h; lv[1] = l;
    bsplit(xa.z, h, l); hv[2] = h; lv[2] = l;
    bsplit(xa.w, h, l); hv[3] = h; lv[3] = l;
    bsplit(xb.x, h, l); hv[4] = h; lv[4] = l;
    bsplit(xb.y, h, l); hv[5] = h; lv[5] = l;
    bsplit(xb.z, h, l); hv[6] = h; lv[6] = l;
    bsplit(xb.w, h, l); hv[7] = h; lv[7] = l;
    *(short8v*)aw0 = hv;
    *(short8v*)aw1 = lv;
  }
  __syncthreads();

  for (int s = 0; s < NKB; ++s) {
    const int cur = s & 1, nxt = cur ^ 1;
    float4 xa2, xb2;
    if (s + 1 < NKB) {
      xa2 = *(const float4*)(xrow + (s + 1) * KB);
      xb2 = *(const float4*)(xrow + (s + 1) * KB + 4);
#pragma unroll
      for (int j = 0; j < 4; ++j) {
        const ushort* gsrc = gB + (size_t)(s + 1) * 16384 + (size_t)j * 512;
        ushort* ldst = &Bb[nxt][(wid * 4 + j) * 512];
        __builtin_amdgcn_global_load_lds(
            (const __attribute__((address_space(1))) void*)gsrc,
            (__attribute__((address_space(3))) void*)ldst, 16, 0, 0);
      }
    }
    // ---- compute K-block s from LDS ----
#pragma unroll
    for (int c2 = 0; c2 < 2; ++c2) {
      const short8v ah = *(const short8v*)&Ab[cur][AIDX(0, arow, c2 * 4 + lg)];
      const short8v al = *(const short8v*)&Ab[cur][AIDX(1, arow, c2 * 4 + lg)];
      const int rb0 = cg * 64 + lr;
      const short8v bh0 = *(const short8v*)&Bb[cur][BIDX(c2, 0, rb0,      lg)];
      const short8v bh1 = *(const short8v*)&Bb[cur][BIDX(c2, 0, rb0 + 16, lg)];
      const short8v bh2 = *(const short8v*)&Bb[cur][BIDX(c2, 0, rb0 + 32, lg)];
      const short8v bh3 = *(const short8v*)&Bb[cur][BIDX(c2, 0, rb0 + 48, lg)];
      const short8v bl0 = *(const short8v*)&Bb[cur][BIDX(c2, 1, rb0,      lg)];
      const short8v bl1 = *(const short8v*)&Bb[cur][BIDX(c2, 1, rb0 + 16, lg)];
      const short8v bl2 = *(const short8v*)&Bb[cur][BIDX(c2, 1, rb0 + 32, lg)];
      const short8v bl3 = *(const short8v*)&Bb[cur][BIDX(c2, 1, rb0 + 48, lg)];
      acc0 = __builtin_amdgcn_mfma_f32_16x16x32_bf16(ah, bh0, acc0, 0, 0, 0);
      acc1 = __builtin_amdgcn_mfma_f32_16x16x32_bf16(ah, bh1, acc1, 0, 0, 0);
      acc2 = __builtin_amdgcn_mfma_f32_16x16x32_bf16(ah, bh2, acc2, 0, 0, 0);
      acc3 = __builtin_amdgcn_mfma_f32_16x16x32_bf16(ah, bh3, acc3, 0, 0, 0);
      acc0 = __builtin_amdgcn_mfma_f32_16x16x32_bf16(ah, bl0, acc0, 0, 0, 0);
      acc1 = __builtin_amdgcn_mfma_f32_16x16x32_bf16(ah, bl1, acc1, 0, 0, 0);
      acc2 = __builtin_amdgcn_mfma_f32_16x16x32_bf16(ah, bl2, acc2, 0, 0, 0);
      acc3 = __builtin_amdgcn_mfma_f32_16x16x32_bf16(ah, bl3, acc3, 0, 0, 0);
      acc0 = __builtin_amdgcn_mfma_f32_16x16x32_bf16(al, bh0, acc0, 0, 0, 0);
      acc1 = __builtin_amdgcn_mfma_f32_16x16x32_bf16(al, bh1, acc1, 0, 0, 0);
      acc2 = __builtin_amdgcn_mfma_f32_16x16x32_bf16(al, bh2, acc2, 0, 0, 0);
      acc3 = __builtin_amdgcn_mfma_f32_16x16x32_bf16(al, bh3, acc3, 0, 0, 0);
    }
    if (s + 1 < NKB) {
      short8v hv, lv; ushort h, l;
      bsplit(xa2.x, h, l); hv[0] = h; lv[0] = l;
      bsplit(xa2.y, h, l); hv[1] = h; lv[1] = l;
      bsplit(xa2.z, h, l); hv[2] = h; lv[2] = l;
      bsplit(xa2.w, h, l); hv[3] = h; lv[3] = l;
      bsplit(xb2.x, h, l); hv[4] = h; lv[4] = l;
      bsplit(xb2.y, h, l); hv[5] = h; lv[5] = l;
      bsplit(xb2.z, h, l); hv[6] = h; lv[6] = l;
      bsplit(xb2.w, h, l); hv[7] = h; lv[7] = l;
      *(short8v*)(aw0 + (size_t)nxt * abufstride) = hv;
      *(short8v*)(aw1 + (size_t)nxt * abufstride) = lv;
    }
    __syncthreads();
  }

  // C layout: col = lane&15 (lr), row = lg*4 + reg (proven r7-r12)
#pragma unroll
  for (int rr = 0; rr < 4; ++rr) {
    const int trow = row0 + mg * 16 + lg * 4 + rr;
    float* srow_p = scores + (size_t)trow * 128 + cg * 64 + lr;
    srow_p[0]  = acc0[rr];
    srow_p[16] = acc1[rr];
    srow_p[32] = acc2[rr];
    srow_p[48] = acc3[rr];
  }
}

// one wave per token: fast path only; near-ties appended to flag list
__global__ __launch_bounds__(512, 4)
void epi_fast(const float* __restrict__ scores,
              const float* __restrict__ br, const float* __restrict__ bn,
              const float* __restrict__ noise,
              float* __restrict__ out_w, float* __restrict__ out_i,
              float* __restrict__ out_s,
              int* __restrict__ flagcnt, int* __restrict__ flaglist)
{
  const int wid  = threadIdx.x >> 6;
  const int lane = threadIdx.x & 63;
  const int t    = blockIdx.x * 8 + wid;

  const float sr = scores[(size_t)t * 128 + lane];
  const float sn = scores[(size_t)t * 128 + 64 + lane];
  const float z  = sn + bn[lane];
  const float sp = fmaxf(z, 0.f) + log1pf(expf(-fabsf(z)));
  const float v  = sr + br[lane] + noise[(size_t)t * NEXP + lane] * sp;

  float m = v;
#pragma unroll
  for (int d = 32; d; d >>= 1) m = fmaxf(m, __shfl_xor(m, d));
  const float p = expf(v - m);
  float sum = p;
#pragma unroll
  for (int d = 32; d; d >>= 1) sum += __shfl_xor(sum, d);
  out_s[(size_t)t * NEXP + lane] = p / sum;

  float cur = v;
  float vals9[9]; int idx9[9];
#pragma unroll
  for (int it = 0; it < 9; ++it) {
    float mx = cur;
#pragma unroll
    for (int d = 32; d; d >>= 1) mx = fmaxf(mx, __shfl_xor(mx, d));
    const unsigned long long b = __ballot(cur == mx);
    const int li = __ffsll(b) - 1;                 // ties -> lowest index
    vals9[it] = mx; idx9[it] = li;
    if (lane == li) cur = -INFINITY;
  }
  bool flagged = false;
#pragma unroll
  for (int q = 0; q < 8; ++q) flagged |= (vals9[q] - vals9[q + 1] < TAU);

  if (flagged) {
    if (lane == 0) {
      const int s = atomicAdd(flagcnt, 1);
      flaglist[s] = t;
    }
    return;                                        // refine_* writes outputs
  }

  float pt[8]; float ws = 0.f;
#pragma unroll
  for (int q = 0; q < 8; ++q) { pt[q] = expf(vals9[q] - m); ws += pt[q]; }
  if (lane < 8) {
    out_w[(size_t)t * 8 + lane] = pt[lane] / ws;
    out_i[(size_t)t * 8 + lane] = (float)idx9[lane];
  }
}

// one WAVE per (flagged token, expert): nf*64 wave-jobs, grid-strided
__global__ __launch_bounds__(512)
void refine_dots(const float* __restrict__ x,
                 const float* __restrict__ Wr, const float* __restrict__ Wn,
                 const float* __restrict__ br, const float* __restrict__ bn,
                 const float* __restrict__ noise,
                 const int* __restrict__ flagcnt, const int* __restrict__ flaglist,
                 double* __restrict__ nv64)
{
  const int nf    = *flagcnt;
  const int lane  = threadIdx.x & 63;
  const int wslot = (blockIdx.x * 512 + threadIdx.x) >> 6;
  const int nwav  = (gridDim.x * 512) >> 6;
  const int total = nf * 64;

  for (int w = wslot; w < total; w += nwav) {
    const int i = w >> 6, e = w & 63;
    const int t = flaglist[i];
    const float* xr  = x  + (size_t)t * KDIM + lane * 4;
    const float* wrr = Wr + (size_t)e * KDIM + lane * 4;
    const float* wnr = Wn + (size_t)e * KDIM + lane * 4;
    double a0 = 0, a1 = 0, c0 = 0, c1 = 0;
#pragma unroll
    for (int q = 0; q < 8; ++q) {
      const float4 xv = *(const float4*)(xr  + q * 256);
      const float4 wv = *(const float4*)(wrr + q * 256);
      const float4 nv = *(const float4*)(wnr + q * 256);
      a0 = fma((double)xv.x, (double)wv.x, a0);
      a1 = fma((double)xv.y, (double)wv.y, a1);
      a0 = fma((double)xv.z, (double)wv.z, a0);
      a1 = fma((double)xv.w, (double)wv.w, a1);
      c0 = fma((double)xv.x, (double)nv.x, c0);
      c1 = fma((double)xv.y, (double)nv.y, c1);
      c0 = fma((double)xv.z, (double)nv.z, c0);
      c1 = fma((double)xv.w, (double)nv.w, c1);
    }
    double ar = a0 + a1, an = c0 + c1;
#pragma unroll
    for (int d = 32; d; d >>= 1) {
      ar += __shfl_xor(ar, d);
      an += __shfl_xor(an, d);
    }
    if (lane == 0) {
      const double rte = ar + (double)br[e];
      const double zz  = an + (double)bn[e];
      const double spd = fmax(zz, 0.0) + log1p(exp(-fabs(zz)));
      nv64[(size_t)i * 64 + e] = rte + (double)noise[(size_t)t * NEXP + e] * spd;
    }
  }
}

// one wave per flagged token: proven fp64 softmax/top-8 tail
__global__ __launch_bounds__(512)
void refine_final(const double* __restrict__ nv64,
                  const int* __restrict__ flagcnt, const int* __restrict__ flaglist,
                  float* __restrict__ out_w, float* __restrict__ out_i,
                  float* __restrict__ out_s)
{
  const int nf    = *flagcnt;
  const int lane  = threadIdx.x & 63;
  const int wslot = (blockIdx.x * 512 + threadIdx.x) >> 6;
  const int nwav  = (gridDim.x * 512) >> 6;

  for (int i = wslot; i < nf; i += nwav) {
    const int t = flaglist[i];
    const double v64 = nv64[(size_t)i * 64 + lane];
    double md = v64;
#pragma unroll
    for (int d = 32; d; d >>= 1) md = fmax(md, __shfl_xor(md, d));
    const double pe = exp(v64 - md);
    double sd = pe;
#pragma unroll
    for (int d = 32; d; d >>= 1) sd += __shfl_xor(sd, d);
    out_s[(size_t)t * NEXP + lane] = (float)(pe / sd);

    double curd = v64;
    double pv8[8]; int pi8[8]; double wsd = 0.0;
#pragma unroll
    for (int it = 0; it < 8; ++it) {
      double mx = curd;
#pragma unroll
      for (int d = 32; d; d >>= 1) mx = fmax(mx, __shfl_xor(mx, d));
      const unsigned long long b = __ballot(curd == mx);
      const int li = __ffsll(b) - 1;
      pv8[it] = __shfl(pe, li); pi8[it] = li; wsd += pv8[it];
      if (lane == li) curd = -1e300;
    }
    if (lane < 8) {
      out_w[(size_t)t * 8 + lane] = (float)(pv8[lane] / wsd);
      out_i[(size_t)t * 8 + lane] = (float)pi8[lane];
    }
  }
}

extern "C" void kernel_launch(void* const* d_in, const int* in_sizes, int n_in,
                              void* d_out, int out_size, void* d_ws, size_t ws_size,
                              hipStream_t stream) {
  const float* x     = (const float*)d_in[0];
  const float* Wr    = (const float*)d_in[1];
  const float* br    = (const float*)d_in[2];
  const float* Wn    = (const float*)d_in[3];
  const float* bn    = (const float*)d_in[4];
  const float* noise = (const float*)d_in[5];

  const int M = in_sizes[0] / KDIM;                  // 16384 tokens
  float*  scores   = (float*)d_ws;                   // [M][128] f32 = 8 MB
  double* nv64     = (double*)d_ws;                  // aliases scores (dead after
                                                     // epi_fast): [i][64] f64
  ushort* Wpk      = (ushort*)(scores + (size_t)M * 128);  // 1 MB packed W
  int*    flagcnt  = (int*)(Wpk + (size_t)32 * 16384);
  int*    flaglist = flagcnt + 1;                    // up to M ints

  float* out   = (float*)d_out;
  float* out_w = out;                                // [M,8]
  float* out_i = out + (size_t)M * 8;                // [M,8] indices as floats
  float* out_s = out + (size_t)M * 16;               // [M,64]

  convert_w<<<dim3(128), dim3(256), 0, stream>>>(Wr, Wn, Wpk, flagcnt);
  gemm_k1<<<dim3(M / BM), dim3(512), 0, stream>>>(x, Wpk, scores);
  epi_fast<<<dim3(M / 8), dim3(512), 0, stream>>>(scores, br, bn, noise,
                                                  out_w, out_i, out_s,
                                                  flagcnt, flaglist);
  refine_dots<<<dim3(1024), dim3(512), 0, stream>>>(x, Wr, Wn, br, bn, noise,
                                                    flagcnt, flaglist, nv64);
  refine_final<<<dim3(256), dim3(512), 0, stream>>>(nv64, flagcnt, flaglist,
                                                    out_w, out_i, out_s);
}